// Round 3
// baseline (151.588 us; speedup 1.0000x reference)
//
#include <hip/hip_runtime.h>

typedef __attribute__((ext_vector_type(8))) short short8;
typedef __attribute__((ext_vector_type(4))) float floatx4;
typedef __attribute__((ext_vector_type(4))) int   intx4;

#define MFMA16(a,b,c) __builtin_amdgcn_mfma_f32_16x16x32_bf16((a),(b),(c),0,0,0)

static __device__ __forceinline__ unsigned short f2bf(float f){
    unsigned int u = __float_as_uint(f);
    u = (u + 0x7FFFu + ((u >> 16) & 1u)) >> 16;
    return (unsigned short)u;
}

// pack two f32 -> 2xbf16 in one u32 (low = first arg)
static __device__ __forceinline__ unsigned int pkbf(float lo, float hi){
    unsigned int r;
    asm("v_cvt_pk_bf16_f32 %0, %1, %2" : "=v"(r) : "v"(lo), "v"(hi));
    return r;
}

// async global->LDS, 16 B/lane; lds base must be wave-uniform, lane i lands at
// base + i*16 (m97/m104). Source address is per-lane (gather) -> lets us store
// XOR-swizzled layouts by permuting the SOURCE, not the destination.
static __device__ __forceinline__ void async16(const unsigned short* g, const unsigned short* l){
    __builtin_amdgcn_global_load_lds(
        (const __attribute__((address_space(1))) unsigned int*)g,
        (__attribute__((address_space(3))) unsigned int*)l, 16, 0, 0);
}

// ---------------------------------------------------------------------------
// Kernel 1: prep = transpose x + convert weights to bf16 + precompute the
// rel-pos bias table Bp[h][token][key] (bf16, pre-scaled by log2e) in exactly
// the S^T-fragment order phase B consumes (key-contiguous).
// ---------------------------------------------------------------------------
__global__ __launch_bounds__(256) void k_prep(const float* __restrict__ x,
                                              unsigned short* __restrict__ xT,
                                              const float* __restrict__ qkvw,
                                              unsigned short* __restrict__ wqkv,
                                              const float* __restrict__ outw,
                                              unsigned short* __restrict__ wout,
                                              const float* __restrict__ rel,
                                              unsigned short* __restrict__ Bp){
    __shared__ unsigned short tile[64][78];
    const int bid = blockIdx.x;
    const int tid = threadIdx.x;
    if (bid < 2048){
        const int c0 = (bid & 7) * 64;
        const int n0 = ((bid >> 3) & 3) * 64;
        const int b  = bid >> 5;
        const int chunk = tid & 7;
        const int r     = tid >> 3;
        const float*    src = x  + (size_t)b * 131072;
        unsigned short* dst = xT + (size_t)b * 131072;
#pragma unroll
        for (int it = 0; it < 2; ++it){
            int c = r + it * 32;
            const float* p = src + (size_t)(c0 + c) * 256 + n0 + chunk * 8;
            float4 f0 = *(const float4*)(p);
            float4 f1 = *(const float4*)(p + 4);
            short8 v;
            v[0]=(short)f2bf(f0.x); v[1]=(short)f2bf(f0.y); v[2]=(short)f2bf(f0.z); v[3]=(short)f2bf(f0.w);
            v[4]=(short)f2bf(f1.x); v[5]=(short)f2bf(f1.y); v[6]=(short)f2bf(f1.z); v[7]=(short)f2bf(f1.w);
            *(short8*)&tile[c][chunk * 8] = v;
        }
        __syncthreads();
#pragma unroll
        for (int it = 0; it < 2; ++it){
            int n = r + it * 32;
            short8 o;
#pragma unroll
            for (int e = 0; e < 8; ++e) o[e] = (short)tile[chunk * 8 + e][n];
            *(short8*)(dst + (size_t)(n0 + n) * 512 + c0 + chunk * 8) = o;
        }
    } else if (bid < 3072){
        int i = (bid - 2048) * 256 + tid;
        const float* s; unsigned short* d; int j;
        if (i < 196608){ s = qkvw; d = wqkv; j = i; }
        else { j = i - 196608; if (j >= 65536) return; s = outw; d = wout; }
        float4 f = *(const float4*)(s + (size_t)j * 4);
        uint2 v;
        v.x = (unsigned int)f2bf(f.x) | ((unsigned int)f2bf(f.y) << 16);
        v.y = (unsigned int)f2bf(f.z) | ((unsigned int)f2bf(f.w) << 16);
        *(uint2*)(d + (size_t)j * 4) = v;
    } else {
        // bias table: idx -> (h, token, key0*4), val = rel[h][th-kh+15][tw-kw+15]*log2e
        int idx   = (bid - 3072) * 256 + tid;          // 0..131071
        int h     = idx >> 14;
        int token = (idx >> 6) & 255;
        int key0  = (idx & 63) << 2;
        int th = token >> 4, tw = token & 15;
        int kh = key0 >> 4,  kw0 = key0 & 15;
        int base = h * 961 + (th - kh + 15) * 31 + (tw - kw0 + 15);
        float v0 = rel[base]     * 1.44269504f;
        float v1 = rel[base - 1] * 1.44269504f;
        float v2 = rel[base - 2] * 1.44269504f;
        float v3 = rel[base - 3] * 1.44269504f;
        uint2 o; o.x = pkbf(v0, v1); o.y = pkbf(v2, v3);
        *(uint2*)(Bp + (size_t)idx * 4) = o;
    }
}

// ---------------------------------------------------------------------------
// Kernel 2: FUSED qkv-projection + attention, one block per (b, h).
// Phase A: DMA double-buffered mini-GEMM with COUNTED vmcnt + raw barriers
//          (T4: prefetched loads stay in flight across barriers, no drain).
// Phase B: swapped-operand attention, bias via MFMA C-init (no LDS softmax
//          reads), pp-fused K/V reads (each K/V fragment read once per wave).
// ---------------------------------------------------------------------------
__global__ __launch_bounds__(512, 2) void k_fused(const unsigned short* __restrict__ xT,
                                                  const unsigned short* __restrict__ wbf,
                                                  const float* __restrict__ qkvb,
                                                  const unsigned short* __restrict__ Bp,
                                                  unsigned short* __restrict__ ao){
    __shared__ unsigned short SH[77824];          // 155,648 B
    const int XS = 0;          // X stage buf0  256x64
    const int WS = 16384;      // W stage buf0  192x64
    const int QS = 28672;      // Q 256x64   (doubles as X stage buf1 in phase A)
    const int KS = 45056;      // K 256x64   (doubles as W stage buf1 in phase A)
    const int VS = 61440;      // V  64x256 (head-major)

    const int bid  = blockIdx.x;
    const int xcd  = bid & 7;
    const int slot = bid >> 3;                    // 0..63
    const int b = xcd * 8 + (slot & 7);           // all 8 heads of a b-octet on one XCD
    const int h = slot >> 3;
    const int tid  = threadIdx.x;
    const int wave = tid >> 6;
    const int lane = tid & 63;
    const int lrow = lane & 15;
    const int lgrp = lane >> 4;
    const int mq = wave >> 1;                     // M-quarter (64 tokens)
    const int nh = wave & 1;                      // N-half (96 cols)

    // ---- phase A: QKV mini-GEMM -------------------------------------------
    floatx4 acc[4][6];
#pragma unroll
    for (int i = 0; i < 4; ++i)
#pragma unroll
        for (int j = 0; j < 6; ++j){ floatx4 z = {0.f,0.f,0.f,0.f}; acc[i][j] = z; }

    const unsigned short* xb = xT + (size_t)(b * 256) * 512;
    const unsigned short* xsrc[4]; int xdo[4];
#pragma unroll
    for (int c = 0; c < 4; ++c){
        int s   = (c * 8 + wave) * 64 + lane;     // 0..2047
        int row = s >> 3, pch = s & 7;
        int sch = pch ^ (row & 7);
        xsrc[c] = xb + (size_t)row * 512 + sch * 8;
        xdo[c]  = (c * 8 + wave) * 512;
    }
    const unsigned short* wsrc[3]; int wdo[3];
#pragma unroll
    for (int c = 0; c < 3; ++c){
        int s   = (c * 8 + wave) * 64 + lane;     // 0..1535
        int row = s >> 3, pch = s & 7;
        int sch = pch ^ (row & 7);
        int grow = (row >> 6) * 512 + h * 64 + (row & 63);   // q/k/v row slices
        wsrc[c] = wbf + (size_t)grow * 512 + sch * 8;
        wdo[c]  = (c * 8 + wave) * 512;
    }

    auto stageA = [&](int XBs, int WBs, int kk){
#pragma unroll
        for (int c = 0; c < 4; ++c) async16(xsrc[c] + kk, &SH[XBs + xdo[c]]);
#pragma unroll
        for (int c = 0; c < 3; ++c) async16(wsrc[c] + kk, &SH[WBs + wdo[c]]);
    };
    auto compA = [&](int XBs, int WBs){
#pragma unroll
        for (int ks = 0; ks < 2; ++ks){
            short8 af[4], bq[6];
#pragma unroll
            for (int mt = 0; mt < 4; ++mt){
                int row = mq * 64 + mt * 16 + lrow;
                int pch = (ks * 4 + lgrp) ^ (row & 7);
                af[mt] = *(const short8*)&SH[XBs + row * 64 + pch * 8];
            }
#pragma unroll
            for (int nt = 0; nt < 6; ++nt){
                int row = nh * 96 + nt * 16 + lrow;
                int pch = (ks * 4 + lgrp) ^ (row & 7);
                bq[nt] = *(const short8*)&SH[WBs + row * 64 + pch * 8];
            }
#pragma unroll
            for (int mt = 0; mt < 4; ++mt)
#pragma unroll
                for (int nt = 0; nt < 6; ++nt)
                    acc[mt][nt] = MFMA16(af[mt], bq[nt], acc[mt][nt]);
        }
    };

    // T4 pipeline: 2 tiles in flight; each wave waits only for ITS tile's 7
    // DMAs (vmcnt(7) leaves the prefetch flying), raw barriers, no drains.
    stageA(XS, WS, 0);                            // tile 0 (7 loads)
    stageA(QS, KS, 64);                           // tile 1 (7 loads)
#pragma unroll
    for (int t2 = 0; t2 < 4; ++t2){
        // even tile 2*t2 in buf0
        asm volatile("s_waitcnt vmcnt(7)" ::: "memory");
        __builtin_amdgcn_s_barrier();
        asm volatile("" ::: "memory");
        compA(XS, WS);
        asm volatile("" ::: "memory");
        if (t2 < 3){
            __builtin_amdgcn_s_barrier();         // all waves done reading buf0
            stageA(XS, WS, t2 * 128 + 128);       // tile 2*t2+2 -> buf0
            asm volatile("s_waitcnt vmcnt(7)" ::: "memory");
        } else {
            asm volatile("s_waitcnt vmcnt(0)" ::: "memory");
        }
        // odd tile 2*t2+1 in buf1
        __builtin_amdgcn_s_barrier();
        asm volatile("" ::: "memory");
        compA(QS, KS);
        asm volatile("" ::: "memory");
        __builtin_amdgcn_s_barrier();             // done reading buf1 (or guard epilogue)
        if (t2 < 3) stageA(QS, KS, t2 * 128 + 192);  // tile 2*t2+3 -> buf1
    }

    // epilogue A: +bias, bf16, scatter into Q/K/V LDS.
    // Q pre-scaled by 0.125*log2e; K rows go to permuted slot rho^-1(token).
#pragma unroll
    for (int mt = 0; mt < 4; ++mt){
#pragma unroll
        for (int nt = 0; nt < 6; ++nt){
            int col = nh * 96 + nt * 16 + lrow;
            int seg = col >> 6, off = col & 63;
            float bv = qkvb[seg * 512 + h * 64 + off];
            int token0 = mq * 64 + mt * 16 + lgrp * 4;
            if (seg == 2){
                int lch = token0 >> 3;
                int pch = (lch & 24) | ((lch & 7) ^ (off & 7));
                uint2 vv;
                vv.x = pkbf(acc[mt][nt][0] + bv, acc[mt][nt][1] + bv);
                vv.y = pkbf(acc[mt][nt][2] + bv, acc[mt][nt][3] + bv);
                *(uint2*)&SH[VS + off * 256 + pch * 8 + (lgrp & 1) * 4] = vv;
            } else if (seg == 1){
#pragma unroll
                for (int r = 0; r < 4; ++r){
                    int token = token0 + r;
                    int kslot = (token & ~0x1C) | ((token & 4) << 2) | ((token & 0x18) >> 1);
                    int pch   = (off >> 3) ^ (kslot & 7);
                    SH[KS + kslot * 64 + pch * 8 + (off & 7)] = f2bf(acc[mt][nt][r] + bv);
                }
            } else {
#pragma unroll
                for (int r = 0; r < 4; ++r){
                    int token = token0 + r;
                    int pch   = (off >> 3) ^ (token & 7);
                    SH[QS + token * 64 + pch * 8 + (off & 7)] =
                        f2bf((acc[mt][nt][r] + bv) * 0.18033688f);
                }
            }
        }
    }
    __syncthreads();

    // ---- phase B: attention (LDS read-only, pp-fused: K/V read ONCE) -------
    short8 aq[2][2];
#pragma unroll
    for (int pp = 0; pp < 2; ++pp)
#pragma unroll
        for (int kc = 0; kc < 2; ++kc){
            int row = wave * 32 + pp * 16 + lrow;
            int pch = (kc * 4 + lgrp) ^ (row & 7);
            aq[pp][kc] = *(const short8*)&SH[QS + row * 64 + pch * 8];
        }

    const unsigned short* bp0 = Bp + ((size_t)h * 256 + wave * 32 + lrow) * 256;

    // S^T = K.Q^T for both pp; C initialized with bias fragments (global bf16)
    floatx4 st0[16], st1[16];
    __builtin_amdgcn_s_setprio(1);
#pragma unroll
    for (int ct = 0; ct < 16; ++ct){
        int key0 = 32 * (ct >> 1) + 8 * lgrp + 4 * (ct & 1);
        uint2 bA = *(const uint2*)(bp0 + key0);
        uint2 bB = *(const uint2*)(bp0 + 4096 + key0);
        int row  = ct * 16 + lrow;
        int pch0 = lgrp ^ (row & 7);
        short8 k0 = *(const short8*)&SH[KS + row * 64 + pch0 * 8];
        short8 k1 = *(const short8*)&SH[KS + row * 64 + (pch0 ^ 4) * 8];
        floatx4 z0, z1;
        z0[0] = __uint_as_float(bA.x << 16);
        z0[1] = __uint_as_float(bA.x & 0xFFFF0000u);
        z0[2] = __uint_as_float(bA.y << 16);
        z0[3] = __uint_as_float(bA.y & 0xFFFF0000u);
        z1[0] = __uint_as_float(bB.x << 16);
        z1[1] = __uint_as_float(bB.x & 0xFFFF0000u);
        z1[2] = __uint_as_float(bB.y << 16);
        z1[3] = __uint_as_float(bB.y & 0xFFFF0000u);
        z0 = MFMA16(k0, aq[0][0], z0);
        z0 = MFMA16(k1, aq[0][1], z0);
        z1 = MFMA16(k0, aq[1][0], z1);
        z1 = MFMA16(k1, aq[1][1], z1);
        st0[ct] = z0; st1[ct] = z1;
    }
    __builtin_amdgcn_s_setprio(0);

    // softmax in exp2 domain, 4 independent partial-sum chains per pp
    float inv0, inv1;
    {
        float p0=0.f,p1=0.f,p2=0.f,p3=0.f;
#pragma unroll
        for (int ct = 0; ct < 16; ++ct){
            float e0 = __builtin_amdgcn_exp2f(st0[ct][0]); st0[ct][0]=e0; p0+=e0;
            float e1 = __builtin_amdgcn_exp2f(st0[ct][1]); st0[ct][1]=e1; p1+=e1;
            float e2 = __builtin_amdgcn_exp2f(st0[ct][2]); st0[ct][2]=e2; p2+=e2;
            float e3 = __builtin_amdgcn_exp2f(st0[ct][3]); st0[ct][3]=e3; p3+=e3;
        }
        float s = (p0+p1)+(p2+p3);
        s += __shfl_xor(s, 16, 64);
        s += __shfl_xor(s, 32, 64);
        inv0 = 1.f / s;
    }
    {
        float p0=0.f,p1=0.f,p2=0.f,p3=0.f;
#pragma unroll
        for (int ct = 0; ct < 16; ++ct){
            float e0 = __builtin_amdgcn_exp2f(st1[ct][0]); st1[ct][0]=e0; p0+=e0;
            float e1 = __builtin_amdgcn_exp2f(st1[ct][1]); st1[ct][1]=e1; p1+=e1;
            float e2 = __builtin_amdgcn_exp2f(st1[ct][2]); st1[ct][2]=e2; p2+=e2;
            float e3 = __builtin_amdgcn_exp2f(st1[ct][3]); st1[ct][3]=e3; p3+=e3;
        }
        float s = (p0+p1)+(p2+p3);
        s += __shfl_xor(s, 16, 64);
        s += __shfl_xor(s, 32, 64);
        inv1 = 1.f / s;
    }

    // pack P^T fragments (lane-local thanks to K slot permutation)
    intx4 pf0[8], pf1[8];
#pragma unroll
    for (int ms = 0; ms < 8; ++ms){
        intx4 t0_, t1_;
        t0_.x = (int)pkbf(st0[2*ms  ][0], st0[2*ms  ][1]);
        t0_.y = (int)pkbf(st0[2*ms  ][2], st0[2*ms  ][3]);
        t0_.z = (int)pkbf(st0[2*ms+1][0], st0[2*ms+1][1]);
        t0_.w = (int)pkbf(st0[2*ms+1][2], st0[2*ms+1][3]);
        pf0[ms] = t0_;
        t1_.x = (int)pkbf(st1[2*ms  ][0], st1[2*ms  ][1]);
        t1_.y = (int)pkbf(st1[2*ms  ][2], st1[2*ms  ][3]);
        t1_.z = (int)pkbf(st1[2*ms+1][0], st1[2*ms+1][1]);
        t1_.w = (int)pkbf(st1[2*ms+1][2], st1[2*ms+1][3]);
        pf1[ms] = t1_;
    }

    // O^T = V^T . P^T, both pp per V-fragment read
    unsigned short* aob = ao + (size_t)(b * 256) * 512 + h * 64;
    const int n0 = wave * 32 + lrow;
    __builtin_amdgcn_s_setprio(1);
#pragma unroll
    for (int dt = 0; dt < 4; ++dt){
        floatx4 a0 = {0.f,0.f,0.f,0.f}, a1 = {0.f,0.f,0.f,0.f};
#pragma unroll
        for (int ms = 0; ms < 8; ++ms){
            int row = dt * 16 + lrow;
            int lch = ms * 4 + lgrp;
            int pch = (lch & 24) | ((lch & 7) ^ (row & 7));
            short8 vb = *(const short8*)&SH[VS + row * 256 + pch * 8];
            a0 = MFMA16(vb, __builtin_bit_cast(short8, pf0[ms]), a0);
            a1 = MFMA16(vb, __builtin_bit_cast(short8, pf1[ms]), a1);
        }
        uint2 o0, o1;
        o0.x = pkbf(a0[0] * inv0, a0[1] * inv0);
        o0.y = pkbf(a0[2] * inv0, a0[3] * inv0);
        *(uint2*)(aob + (size_t)n0 * 512 + dt * 16 + lgrp * 4) = o0;
        o1.x = pkbf(a1[0] * inv1, a1[1] * inv1);
        o1.y = pkbf(a1[2] * inv1, a1[3] * inv1);
        *(uint2*)(aob + (size_t)(n0 + 16) * 512 + dt * 16 + lgrp * 4) = o1;
    }
    __builtin_amdgcn_s_setprio(0);
}

// ---------------------------------------------------------------------------
// Kernel 3: out projection, double-buffered with COUNTED vmcnt (T4), XCD
// swizzle, chunk-XOR LDS swizzle, fp32 out[b,o,n].
// ---------------------------------------------------------------------------
__global__ __launch_bounds__(256, 2) void k_out(const unsigned short* __restrict__ ao,
                                                const unsigned short* __restrict__ wbf,
                                                const float* __restrict__ bias,
                                                float* __restrict__ out){
    __shared__ unsigned short Ash[2][2][128][32];   // [dbuf][kslice][row][col]
    __shared__ unsigned short Bsh[2][2][128][32];
    const int bid  = blockIdx.x;
    const int xcd  = bid & 7;
    const int slot = bid >> 3;
    const int t0 = (xcd * 16 + (slot & 15)) * 128;
    const int o0 = (slot >> 4) * 128;
    const int tid  = threadIdx.x;
    const int wave = tid >> 6;
    const int lane = tid & 63;
    const int lrow = lane & 15;
    const int wm   = (wave >> 1) * 64;
    const int wn   = (wave & 1) * 64;
    const int ld_row = wave * 32 + (lane >> 2);
    const int ld_col = (((lane & 3) ^ ((lane >> 3) & 3))) * 8;
    const int pcho = (((lane >> 4) ^ ((lrow >> 1) & 3))) * 8;

    floatx4 acc[4][4];
#pragma unroll
    for (int i = 0; i < 4; ++i)
#pragma unroll
        for (int j = 0; j < 4; ++j){ floatx4 z = {0.f,0.f,0.f,0.f}; acc[i][j] = z; }

    const unsigned short* gA = wbf + (size_t)(o0 + ld_row) * 512 + ld_col;
    const unsigned short* gB = ao  + (size_t)(t0 + ld_row) * 512 + ld_col;

    auto stage = [&](int d, int kk){
        async16(gA + kk,                 &Ash[d][0][wave * 32][0]);
        async16(gA + kk + 16 * 512,      &Ash[d][0][wave * 32 + 16][0]);
        async16(gA + kk + 32,            &Ash[d][1][wave * 32][0]);
        async16(gA + kk + 32 + 16 * 512, &Ash[d][1][wave * 32 + 16][0]);
        async16(gB + kk,                 &Bsh[d][0][wave * 32][0]);
        async16(gB + kk + 16 * 512,      &Bsh[d][0][wave * 32 + 16][0]);
        async16(gB + kk + 32,            &Bsh[d][1][wave * 32][0]);
        async16(gB + kk + 32 + 16 * 512, &Bsh[d][1][wave * 32 + 16][0]);
    };
    auto comp = [&](int d){
#pragma unroll
        for (int s = 0; s < 2; ++s){
            short8 af[4], bq[4];
#pragma unroll
            for (int mt = 0; mt < 4; ++mt) af[mt] = *(const short8*)&Ash[d][s][wm + mt*16 + lrow][pcho];
#pragma unroll
            for (int nt = 0; nt < 4; ++nt) bq[nt] = *(const short8*)&Bsh[d][s][wn + nt*16 + lrow][pcho];
#pragma unroll
            for (int mt = 0; mt < 4; ++mt)
#pragma unroll
                for (int nt = 0; nt < 4; ++nt)
                    acc[mt][nt] = MFMA16(af[mt], bq[nt], acc[mt][nt]);
        }
    };

    stage(0, 0);
    stage(1, 64);
#pragma unroll
    for (int t2 = 0; t2 < 4; ++t2){
        asm volatile("s_waitcnt vmcnt(8)" ::: "memory");
        __builtin_amdgcn_s_barrier();
        asm volatile("" ::: "memory");
        comp(0);
        asm volatile("" ::: "memory");
        if (t2 < 3){
            __builtin_amdgcn_s_barrier();
            stage(0, t2 * 128 + 128);
            asm volatile("s_waitcnt vmcnt(8)" ::: "memory");
        } else {
            asm volatile("s_waitcnt vmcnt(0)" ::: "memory");
        }
        __builtin_amdgcn_s_barrier();
        asm volatile("" ::: "memory");
        comp(1);
        asm volatile("" ::: "memory");
        __builtin_amdgcn_s_barrier();
        if (t2 < 3) stage(1, t2 * 128 + 192);
    }
#pragma unroll
    for (int mt = 0; mt < 4; ++mt){
        int orow0 = o0 + wm + mt*16 + (lane >> 4) * 4;
#pragma unroll
        for (int nt = 0; nt < 4; ++nt){
            int tcol = t0 + wn + nt*16 + lrow;
            int bb = tcol >> 8, nn = tcol & 255;
#pragma unroll
            for (int r = 0; r < 4; ++r){
                float bv = bias[orow0 + r];
                out[(size_t)(bb * 512 + orow0 + r) * 256 + nn] = acc[mt][nt][r] + bv;
            }
        }
    }
}

// ---------------------------------------------------------------------------
extern "C" void kernel_launch(void* const* d_in, const int* in_sizes, int n_in,
                              void* d_out, int out_size, void* d_ws, size_t ws_size,
                              hipStream_t stream){
    const float* x    = (const float*)d_in[0];
    const float* qkvw = (const float*)d_in[1];
    const float* qkvb = (const float*)d_in[2];
    const float* outw = (const float*)d_in[3];
    const float* outb = (const float*)d_in[4];
    const float* rel  = (const float*)d_in[5];
    float* out = (float*)d_out;

    // workspace: XT (16 MiB) | AO (16 MiB) | wqkv 1.5M | wout 0.5M | Bp 1M
    const size_t XT_OFF = 0;
    const size_t AO_OFF = 16777216;
    const size_t W_OFF  = 33554432;
    const size_t NEED   = W_OFF + 4194304;
    if (ws_size < NEED) return;

    char* ws = (char*)d_ws;
    unsigned short* xT = (unsigned short*)(ws + XT_OFF);
    unsigned short* ao = (unsigned short*)(ws + AO_OFF);
    unsigned short* wqkv_bf = (unsigned short*)(ws + W_OFF);
    unsigned short* wout_bf = (unsigned short*)(ws + W_OFF + 2097152);
    unsigned short* Bp      = (unsigned short*)(ws + W_OFF + 2621440);

    hipLaunchKernelGGL(k_prep,  dim3(3584), dim3(256), 0, stream,
                       x, xT, qkvw, wqkv_bf, outw, wout_bf, rel, Bp);
    hipLaunchKernelGGL(k_fused, dim3(512),  dim3(512), 0, stream,
                       xT, wqkv_bf, qkvb, Bp, ao);
    hipLaunchKernelGGL(k_out,   dim3(512),  dim3(256), 0, stream,
                       ao, wout_bf, outb, out);
}

// Round 4
// 150.604 us; speedup vs baseline: 1.0065x; 1.0065x over previous
//
#include <hip/hip_runtime.h>

typedef __attribute__((ext_vector_type(8))) short short8;
typedef __attribute__((ext_vector_type(4))) float floatx4;
typedef __attribute__((ext_vector_type(4))) int   intx4;

#define MFMA16(a,b,c) __builtin_amdgcn_mfma_f32_16x16x32_bf16((a),(b),(c),0,0,0)

static __device__ __forceinline__ unsigned short f2bf(float f){
    unsigned int u = __float_as_uint(f);
    u = (u + 0x7FFFu + ((u >> 16) & 1u)) >> 16;
    return (unsigned short)u;
}

// pack two f32 -> 2xbf16 in one u32 (low = first arg)
static __device__ __forceinline__ unsigned int pkbf(float lo, float hi){
    unsigned int r;
    asm("v_cvt_pk_bf16_f32 %0, %1, %2" : "=v"(r) : "v"(lo), "v"(hi));
    return r;
}

// async global->LDS, 16 B/lane; lds base must be wave-uniform, lane i lands at
// base + i*16 (m97/m104). Source address is per-lane (gather) -> lets us store
// XOR-swizzled layouts by permuting the SOURCE, not the destination.
static __device__ __forceinline__ void async16(const unsigned short* g, const unsigned short* l){
    __builtin_amdgcn_global_load_lds(
        (const __attribute__((address_space(1))) unsigned int*)g,
        (__attribute__((address_space(3))) unsigned int*)l, 16, 0, 0);
}

// ---------------------------------------------------------------------------
// Kernel 1: prep = transpose x + convert weights to bf16 + precompute the
// rel-pos bias table Bp in PER-LANE FRAGMENT ORDER:
//   entry e = ((((h*8+wave)*2+pp)*16+ct)*64+lane)  ->  uint2 (4 bf16 keys)
// so k_fused's hoisted loads are fully coalesced (512 B per wave-instr).
// Values pre-scaled by log2e.
// ---------------------------------------------------------------------------
__global__ __launch_bounds__(256) void k_prep(const float* __restrict__ x,
                                              unsigned short* __restrict__ xT,
                                              const float* __restrict__ qkvw,
                                              unsigned short* __restrict__ wqkv,
                                              const float* __restrict__ outw,
                                              unsigned short* __restrict__ wout,
                                              const float* __restrict__ rel,
                                              unsigned short* __restrict__ Bp){
    __shared__ unsigned short tile[64][78];
    const int bid = blockIdx.x;
    const int tid = threadIdx.x;
    if (bid < 2048){
        const int c0 = (bid & 7) * 64;
        const int n0 = ((bid >> 3) & 3) * 64;
        const int b  = bid >> 5;
        const int chunk = tid & 7;
        const int r     = tid >> 3;
        const float*    src = x  + (size_t)b * 131072;
        unsigned short* dst = xT + (size_t)b * 131072;
#pragma unroll
        for (int it = 0; it < 2; ++it){
            int c = r + it * 32;
            const float* p = src + (size_t)(c0 + c) * 256 + n0 + chunk * 8;
            float4 f0 = *(const float4*)(p);
            float4 f1 = *(const float4*)(p + 4);
            short8 v;
            v[0]=(short)f2bf(f0.x); v[1]=(short)f2bf(f0.y); v[2]=(short)f2bf(f0.z); v[3]=(short)f2bf(f0.w);
            v[4]=(short)f2bf(f1.x); v[5]=(short)f2bf(f1.y); v[6]=(short)f2bf(f1.z); v[7]=(short)f2bf(f1.w);
            *(short8*)&tile[c][chunk * 8] = v;
        }
        __syncthreads();
#pragma unroll
        for (int it = 0; it < 2; ++it){
            int n = r + it * 32;
            short8 o;
#pragma unroll
            for (int e = 0; e < 8; ++e) o[e] = (short)tile[chunk * 8 + e][n];
            *(short8*)(dst + (size_t)(n0 + n) * 512 + c0 + chunk * 8) = o;
        }
    } else if (bid < 3072){
        int i = (bid - 2048) * 256 + tid;
        const float* s; unsigned short* d; int j;
        if (i < 196608){ s = qkvw; d = wqkv; j = i; }
        else { j = i - 196608; if (j >= 65536) return; s = outw; d = wout; }
        float4 f = *(const float4*)(s + (size_t)j * 4);
        uint2 v;
        v.x = (unsigned int)f2bf(f.x) | ((unsigned int)f2bf(f.y) << 16);
        v.y = (unsigned int)f2bf(f.z) | ((unsigned int)f2bf(f.w) << 16);
        *(uint2*)(d + (size_t)j * 4) = v;
    } else {
        // bias table in per-lane fragment order (see header comment)
        int idx  = (bid - 3072) * 256 + tid;           // 0..131071
        int lane = idx & 63;
        int ct   = (idx >> 6) & 15;
        int pp   = (idx >> 10) & 1;
        int wv   = (idx >> 11) & 7;
        int h    = idx >> 14;
        int token = wv * 32 + pp * 16 + (lane & 15);
        int key0  = 32 * (ct >> 1) + 8 * (lane >> 4) + 4 * (ct & 1);
        int th = token >> 4, tw = token & 15;
        int kh = key0 >> 4,  kw0 = key0 & 15;
        int base = h * 961 + (th - kh + 15) * 31 + (tw - kw0 + 15);
        float v0 = rel[base]     * 1.44269504f;
        float v1 = rel[base - 1] * 1.44269504f;
        float v2 = rel[base - 2] * 1.44269504f;
        float v3 = rel[base - 3] * 1.44269504f;
        uint2 o; o.x = pkbf(v0, v1); o.y = pkbf(v2, v3);
        *(uint2*)(Bp + (size_t)idx * 4) = o;
    }
}

// ---------------------------------------------------------------------------
// Kernel 2: FUSED qkv-projection + attention, one block per (b, h).
// Bias loads HOISTED to kernel entry (coalesced, fly during phase A; the
// "memory"-clobbered barrier asm pins them above the loop; issued oldest so
// the counted vmcnt(7) semantics in the T4 pipeline are preserved).
// Phase A: DMA double-buffered mini-GEMM, counted vmcnt + raw barriers.
// Phase B: swapped-operand attention, bias via MFMA C-init, pp-fused K/V.
// ---------------------------------------------------------------------------
__global__ __launch_bounds__(512, 2) void k_fused(const unsigned short* __restrict__ xT,
                                                  const unsigned short* __restrict__ wbf,
                                                  const float* __restrict__ qkvb,
                                                  const unsigned short* __restrict__ Bp,
                                                  unsigned short* __restrict__ ao){
    __shared__ unsigned short SH[77824];          // 155,648 B
    const int XS = 0;          // X stage buf0  256x64
    const int WS = 16384;      // W stage buf0  192x64
    const int QS = 28672;      // Q 256x64   (doubles as X stage buf1 in phase A)
    const int KS = 45056;      // K 256x64   (doubles as W stage buf1 in phase A)
    const int VS = 61440;      // V  64x256 (head-major)

    const int bid  = blockIdx.x;
    const int xcd  = bid & 7;
    const int slot = bid >> 3;                    // 0..63
    const int b = xcd * 8 + (slot & 7);           // all 8 heads of a b-octet on one XCD
    const int h = slot >> 3;
    const int tid  = threadIdx.x;
    const int wave = tid >> 6;
    const int lane = tid & 63;
    const int lrow = lane & 15;
    const int lgrp = lane >> 4;
    const int mq = wave >> 1;                     // M-quarter (64 tokens)
    const int nh = wave & 1;                      // N-half (96 cols)

    // ---- hoisted bias loads (issued FIRST -> oldest in vmcnt order) -------
    const uint2* bpw = (const uint2*)Bp + (((size_t)h * 8 + wave) * 2) * 1024 + lane;
    uint2 bA[16], bB[16];
#pragma unroll
    for (int ct = 0; ct < 16; ++ct){
        bA[ct] = bpw[ct * 64];
        bB[ct] = bpw[(16 + ct) * 64];
    }

    // ---- phase A: QKV mini-GEMM -------------------------------------------
    floatx4 acc[4][6];
#pragma unroll
    for (int i = 0; i < 4; ++i)
#pragma unroll
        for (int j = 0; j < 6; ++j){ floatx4 z = {0.f,0.f,0.f,0.f}; acc[i][j] = z; }

    const unsigned short* xb = xT + (size_t)(b * 256) * 512;
    const unsigned short* xsrc[4]; int xdo[4];
#pragma unroll
    for (int c = 0; c < 4; ++c){
        int s   = (c * 8 + wave) * 64 + lane;     // 0..2047
        int row = s >> 3, pch = s & 7;
        int sch = pch ^ (row & 7);
        xsrc[c] = xb + (size_t)row * 512 + sch * 8;
        xdo[c]  = (c * 8 + wave) * 512;
    }
    const unsigned short* wsrc[3]; int wdo[3];
#pragma unroll
    for (int c = 0; c < 3; ++c){
        int s   = (c * 8 + wave) * 64 + lane;     // 0..1535
        int row = s >> 3, pch = s & 7;
        int sch = pch ^ (row & 7);
        int grow = (row >> 6) * 512 + h * 64 + (row & 63);   // q/k/v row slices
        wsrc[c] = wbf + (size_t)grow * 512 + sch * 8;
        wdo[c]  = (c * 8 + wave) * 512;
    }

    auto stageA = [&](int XBs, int WBs, int kk){
#pragma unroll
        for (int c = 0; c < 4; ++c) async16(xsrc[c] + kk, &SH[XBs + xdo[c]]);
#pragma unroll
        for (int c = 0; c < 3; ++c) async16(wsrc[c] + kk, &SH[WBs + wdo[c]]);
    };
    auto compA = [&](int XBs, int WBs){
#pragma unroll
        for (int ks = 0; ks < 2; ++ks){
            short8 af[4], bq[6];
#pragma unroll
            for (int mt = 0; mt < 4; ++mt){
                int row = mq * 64 + mt * 16 + lrow;
                int pch = (ks * 4 + lgrp) ^ (row & 7);
                af[mt] = *(const short8*)&SH[XBs + row * 64 + pch * 8];
            }
#pragma unroll
            for (int nt = 0; nt < 6; ++nt){
                int row = nh * 96 + nt * 16 + lrow;
                int pch = (ks * 4 + lgrp) ^ (row & 7);
                bq[nt] = *(const short8*)&SH[WBs + row * 64 + pch * 8];
            }
#pragma unroll
            for (int mt = 0; mt < 4; ++mt)
#pragma unroll
                for (int nt = 0; nt < 6; ++nt)
                    acc[mt][nt] = MFMA16(af[mt], bq[nt], acc[mt][nt]);
        }
    };

    // T4 pipeline: 2 tiles in flight; counted vmcnt leaves prefetch flying.
    stageA(XS, WS, 0);                            // tile 0 (7 loads)
    stageA(QS, KS, 64);                           // tile 1 (7 loads)
#pragma unroll
    for (int t2 = 0; t2 < 4; ++t2){
        // even tile 2*t2 in buf0
        asm volatile("s_waitcnt vmcnt(7)" ::: "memory");
        __builtin_amdgcn_s_barrier();
        asm volatile("" ::: "memory");
        compA(XS, WS);
        asm volatile("" ::: "memory");
        if (t2 < 3){
            __builtin_amdgcn_s_barrier();         // all waves done reading buf0
            stageA(XS, WS, t2 * 128 + 128);       // tile 2*t2+2 -> buf0
            asm volatile("s_waitcnt vmcnt(7)" ::: "memory");
        } else {
            asm volatile("s_waitcnt vmcnt(0)" ::: "memory");
        }
        // odd tile 2*t2+1 in buf1
        __builtin_amdgcn_s_barrier();
        asm volatile("" ::: "memory");
        compA(QS, KS);
        asm volatile("" ::: "memory");
        __builtin_amdgcn_s_barrier();             // done reading buf1 (or guard epilogue)
        if (t2 < 3) stageA(QS, KS, t2 * 128 + 192);  // tile 2*t2+3 -> buf1
    }

    // epilogue A: +bias, bf16, scatter into Q/K/V LDS.
    // Q pre-scaled by 0.125*log2e; K rows go to permuted slot rho^-1(token).
#pragma unroll
    for (int mt = 0; mt < 4; ++mt){
#pragma unroll
        for (int nt = 0; nt < 6; ++nt){
            int col = nh * 96 + nt * 16 + lrow;
            int seg = col >> 6, off = col & 63;
            float bv = qkvb[seg * 512 + h * 64 + off];
            int token0 = mq * 64 + mt * 16 + lgrp * 4;
            if (seg == 2){
                int lch = token0 >> 3;
                int pch = (lch & 24) | ((lch & 7) ^ (off & 7));
                uint2 vv;
                vv.x = pkbf(acc[mt][nt][0] + bv, acc[mt][nt][1] + bv);
                vv.y = pkbf(acc[mt][nt][2] + bv, acc[mt][nt][3] + bv);
                *(uint2*)&SH[VS + off * 256 + pch * 8 + (lgrp & 1) * 4] = vv;
            } else if (seg == 1){
#pragma unroll
                for (int r = 0; r < 4; ++r){
                    int token = token0 + r;
                    int kslot = (token & ~0x1C) | ((token & 4) << 2) | ((token & 0x18) >> 1);
                    int pch   = (off >> 3) ^ (kslot & 7);
                    SH[KS + kslot * 64 + pch * 8 + (off & 7)] = f2bf(acc[mt][nt][r] + bv);
                }
            } else {
#pragma unroll
                for (int r = 0; r < 4; ++r){
                    int token = token0 + r;
                    int pch   = (off >> 3) ^ (token & 7);
                    SH[QS + token * 64 + pch * 8 + (off & 7)] =
                        f2bf((acc[mt][nt][r] + bv) * 0.18033688f);
                }
            }
        }
    }
    __syncthreads();

    // ---- phase B: attention (LDS read-only, pp-fused: K/V read ONCE) -------
    short8 aq[2][2];
#pragma unroll
    for (int pp = 0; pp < 2; ++pp)
#pragma unroll
        for (int kc = 0; kc < 2; ++kc){
            int row = wave * 32 + pp * 16 + lrow;
            int pch = (kc * 4 + lgrp) ^ (row & 7);
            aq[pp][kc] = *(const short8*)&SH[QS + row * 64 + pch * 8];
        }

    // S^T = K.Q^T for both pp; C initialized with (register-resident) bias
    floatx4 st0[16], st1[16];
    __builtin_amdgcn_s_setprio(1);
#pragma unroll
    for (int ct = 0; ct < 16; ++ct){
        int row  = ct * 16 + lrow;
        int pch0 = lgrp ^ (row & 7);
        short8 k0 = *(const short8*)&SH[KS + row * 64 + pch0 * 8];
        short8 k1 = *(const short8*)&SH[KS + row * 64 + (pch0 ^ 4) * 8];
        floatx4 z0, z1;
        z0[0] = __uint_as_float(bA[ct].x << 16);
        z0[1] = __uint_as_float(bA[ct].x & 0xFFFF0000u);
        z0[2] = __uint_as_float(bA[ct].y << 16);
        z0[3] = __uint_as_float(bA[ct].y & 0xFFFF0000u);
        z1[0] = __uint_as_float(bB[ct].x << 16);
        z1[1] = __uint_as_float(bB[ct].x & 0xFFFF0000u);
        z1[2] = __uint_as_float(bB[ct].y << 16);
        z1[3] = __uint_as_float(bB[ct].y & 0xFFFF0000u);
        z0 = MFMA16(k0, aq[0][0], z0);
        z0 = MFMA16(k1, aq[0][1], z0);
        z1 = MFMA16(k0, aq[1][0], z1);
        z1 = MFMA16(k1, aq[1][1], z1);
        st0[ct] = z0; st1[ct] = z1;
    }
    __builtin_amdgcn_s_setprio(0);

    // softmax in exp2 domain, 4 independent partial-sum chains per pp
    float inv0, inv1;
    {
        float p0=0.f,p1=0.f,p2=0.f,p3=0.f;
#pragma unroll
        for (int ct = 0; ct < 16; ++ct){
            float e0 = __builtin_amdgcn_exp2f(st0[ct][0]); st0[ct][0]=e0; p0+=e0;
            float e1 = __builtin_amdgcn_exp2f(st0[ct][1]); st0[ct][1]=e1; p1+=e1;
            float e2 = __builtin_amdgcn_exp2f(st0[ct][2]); st0[ct][2]=e2; p2+=e2;
            float e3 = __builtin_amdgcn_exp2f(st0[ct][3]); st0[ct][3]=e3; p3+=e3;
        }
        float s = (p0+p1)+(p2+p3);
        s += __shfl_xor(s, 16, 64);
        s += __shfl_xor(s, 32, 64);
        inv0 = 1.f / s;
    }
    {
        float p0=0.f,p1=0.f,p2=0.f,p3=0.f;
#pragma unroll
        for (int ct = 0; ct < 16; ++ct){
            float e0 = __builtin_amdgcn_exp2f(st1[ct][0]); st1[ct][0]=e0; p0+=e0;
            float e1 = __builtin_amdgcn_exp2f(st1[ct][1]); st1[ct][1]=e1; p1+=e1;
            float e2 = __builtin_amdgcn_exp2f(st1[ct][2]); st1[ct][2]=e2; p2+=e2;
            float e3 = __builtin_amdgcn_exp2f(st1[ct][3]); st1[ct][3]=e3; p3+=e3;
        }
        float s = (p0+p1)+(p2+p3);
        s += __shfl_xor(s, 16, 64);
        s += __shfl_xor(s, 32, 64);
        inv1 = 1.f / s;
    }

    // pack P^T fragments (lane-local thanks to K slot permutation)
    intx4 pf0[8], pf1[8];
#pragma unroll
    for (int ms = 0; ms < 8; ++ms){
        intx4 t0_, t1_;
        t0_.x = (int)pkbf(st0[2*ms  ][0], st0[2*ms  ][1]);
        t0_.y = (int)pkbf(st0[2*ms  ][2], st0[2*ms  ][3]);
        t0_.z = (int)pkbf(st0[2*ms+1][0], st0[2*ms+1][1]);
        t0_.w = (int)pkbf(st0[2*ms+1][2], st0[2*ms+1][3]);
        pf0[ms] = t0_;
        t1_.x = (int)pkbf(st1[2*ms  ][0], st1[2*ms  ][1]);
        t1_.y = (int)pkbf(st1[2*ms  ][2], st1[2*ms  ][3]);
        t1_.z = (int)pkbf(st1[2*ms+1][0], st1[2*ms+1][1]);
        t1_.w = (int)pkbf(st1[2*ms+1][2], st1[2*ms+1][3]);
        pf1[ms] = t1_;
    }

    // O^T = V^T . P^T, both pp per V-fragment read
    unsigned short* aob = ao + (size_t)(b * 256) * 512 + h * 64;
    const int n0 = wave * 32 + lrow;
    __builtin_amdgcn_s_setprio(1);
#pragma unroll
    for (int dt = 0; dt < 4; ++dt){
        floatx4 a0 = {0.f,0.f,0.f,0.f}, a1 = {0.f,0.f,0.f,0.f};
#pragma unroll
        for (int ms = 0; ms < 8; ++ms){
            int row = dt * 16 + lrow;
            int lch = ms * 4 + lgrp;
            int pch = (lch & 24) | ((lch & 7) ^ (row & 7));
            short8 vb = *(const short8*)&SH[VS + row * 256 + pch * 8];
            a0 = MFMA16(vb, __builtin_bit_cast(short8, pf0[ms]), a0);
            a1 = MFMA16(vb, __builtin_bit_cast(short8, pf1[ms]), a1);
        }
        uint2 o0, o1;
        o0.x = pkbf(a0[0] * inv0, a0[1] * inv0);
        o0.y = pkbf(a0[2] * inv0, a0[3] * inv0);
        *(uint2*)(aob + (size_t)n0 * 512 + dt * 16 + lgrp * 4) = o0;
        o1.x = pkbf(a1[0] * inv1, a1[1] * inv1);
        o1.y = pkbf(a1[2] * inv1, a1[3] * inv1);
        *(uint2*)(aob + (size_t)(n0 + 16) * 512 + dt * 16 + lgrp * 4) = o1;
    }
    __builtin_amdgcn_s_setprio(0);
}

// ---------------------------------------------------------------------------
// Kernel 3: out projection, double-buffered with COUNTED vmcnt (T4), XCD
// swizzle, chunk-XOR LDS swizzle, fp32 out[b,o,n].
// ---------------------------------------------------------------------------
__global__ __launch_bounds__(256, 2) void k_out(const unsigned short* __restrict__ ao,
                                                const unsigned short* __restrict__ wbf,
                                                const float* __restrict__ bias,
                                                float* __restrict__ out){
    __shared__ unsigned short Ash[2][2][128][32];   // [dbuf][kslice][row][col]
    __shared__ unsigned short Bsh[2][2][128][32];
    const int bid  = blockIdx.x;
    const int xcd  = bid & 7;
    const int slot = bid >> 3;
    const int t0 = (xcd * 16 + (slot & 15)) * 128;
    const int o0 = (slot >> 4) * 128;
    const int tid  = threadIdx.x;
    const int wave = tid >> 6;
    const int lane = tid & 63;
    const int lrow = lane & 15;
    const int wm   = (wave >> 1) * 64;
    const int wn   = (wave & 1) * 64;
    const int ld_row = wave * 32 + (lane >> 2);
    const int ld_col = (((lane & 3) ^ ((lane >> 3) & 3))) * 8;
    const int pcho = (((lane >> 4) ^ ((lrow >> 1) & 3))) * 8;

    floatx4 acc[4][4];
#pragma unroll
    for (int i = 0; i < 4; ++i)
#pragma unroll
        for (int j = 0; j < 4; ++j){ floatx4 z = {0.f,0.f,0.f,0.f}; acc[i][j] = z; }

    const unsigned short* gA = wbf + (size_t)(o0 + ld_row) * 512 + ld_col;
    const unsigned short* gB = ao  + (size_t)(t0 + ld_row) * 512 + ld_col;

    auto stage = [&](int d, int kk){
        async16(gA + kk,                 &Ash[d][0][wave * 32][0]);
        async16(gA + kk + 16 * 512,      &Ash[d][0][wave * 32 + 16][0]);
        async16(gA + kk + 32,            &Ash[d][1][wave * 32][0]);
        async16(gA + kk + 32 + 16 * 512, &Ash[d][1][wave * 32 + 16][0]);
        async16(gB + kk,                 &Bsh[d][0][wave * 32][0]);
        async16(gB + kk + 16 * 512,      &Bsh[d][0][wave * 32 + 16][0]);
        async16(gB + kk + 32,            &Bsh[d][1][wave * 32][0]);
        async16(gB + kk + 32 + 16 * 512, &Bsh[d][1][wave * 32 + 16][0]);
    };
    auto comp = [&](int d){
#pragma unroll
        for (int s = 0; s < 2; ++s){
            short8 af[4], bq[4];
#pragma unroll
            for (int mt = 0; mt < 4; ++mt) af[mt] = *(const short8*)&Ash[d][s][wm + mt*16 + lrow][pcho];
#pragma unroll
            for (int nt = 0; nt < 4; ++nt) bq[nt] = *(const short8*)&Bsh[d][s][wn + nt*16 + lrow][pcho];
#pragma unroll
            for (int mt = 0; mt < 4; ++mt)
#pragma unroll
                for (int nt = 0; nt < 4; ++nt)
                    acc[mt][nt] = MFMA16(af[mt], bq[nt], acc[mt][nt]);
        }
    };

    stage(0, 0);
    stage(1, 64);
#pragma unroll
    for (int t2 = 0; t2 < 4; ++t2){
        asm volatile("s_waitcnt vmcnt(8)" ::: "memory");
        __builtin_amdgcn_s_barrier();
        asm volatile("" ::: "memory");
        comp(0);
        asm volatile("" ::: "memory");
        if (t2 < 3){
            __builtin_amdgcn_s_barrier();
            stage(0, t2 * 128 + 128);
            asm volatile("s_waitcnt vmcnt(8)" ::: "memory");
        } else {
            asm volatile("s_waitcnt vmcnt(0)" ::: "memory");
        }
        __builtin_amdgcn_s_barrier();
        asm volatile("" ::: "memory");
        comp(1);
        asm volatile("" ::: "memory");
        __builtin_amdgcn_s_barrier();
        if (t2 < 3) stage(1, t2 * 128 + 192);
    }
#pragma unroll
    for (int mt = 0; mt < 4; ++mt){
        int orow0 = o0 + wm + mt*16 + (lane >> 4) * 4;
#pragma unroll
        for (int nt = 0; nt < 4; ++nt){
            int tcol = t0 + wn + nt*16 + lrow;
            int bb = tcol >> 8, nn = tcol & 255;
#pragma unroll
            for (int r = 0; r < 4; ++r){
                float bv = bias[orow0 + r];
                out[(size_t)(bb * 512 + orow0 + r) * 256 + nn] = acc[mt][nt][r] + bv;
            }
        }
    }
}

// ---------------------------------------------------------------------------
extern "C" void kernel_launch(void* const* d_in, const int* in_sizes, int n_in,
                              void* d_out, int out_size, void* d_ws, size_t ws_size,
                              hipStream_t stream){
    const float* x    = (const float*)d_in[0];
    const float* qkvw = (const float*)d_in[1];
    const float* qkvb = (const float*)d_in[2];
    const float* outw = (const float*)d_in[3];
    const float* outb = (const float*)d_in[4];
    const float* rel  = (const float*)d_in[5];
    float* out = (float*)d_out;

    // workspace: XT (16 MiB) | AO (16 MiB) | wqkv 1.5M | wout 0.5M | Bp 1M
    const size_t XT_OFF = 0;
    const size_t AO_OFF = 16777216;
    const size_t W_OFF  = 33554432;
    const size_t NEED   = W_OFF + 4194304;
    if (ws_size < NEED) return;

    char* ws = (char*)d_ws;
    unsigned short* xT = (unsigned short*)(ws + XT_OFF);
    unsigned short* ao = (unsigned short*)(ws + AO_OFF);
    unsigned short* wqkv_bf = (unsigned short*)(ws + W_OFF);
    unsigned short* wout_bf = (unsigned short*)(ws + W_OFF + 2097152);
    unsigned short* Bp      = (unsigned short*)(ws + W_OFF + 2621440);

    hipLaunchKernelGGL(k_prep,  dim3(3584), dim3(256), 0, stream,
                       x, xT, qkvw, wqkv_bf, outw, wout_bf, rel, Bp);
    hipLaunchKernelGGL(k_fused, dim3(512),  dim3(512), 0, stream,
                       xT, wqkv_bf, qkvb, Bp, ao);
    hipLaunchKernelGGL(k_out,   dim3(512),  dim3(256), 0, stream,
                       ao, wout_bf, outb, out);
}

// Round 5
// 148.231 us; speedup vs baseline: 1.0226x; 1.0160x over previous
//
#include <hip/hip_runtime.h>

typedef __attribute__((ext_vector_type(8))) short short8;
typedef __attribute__((ext_vector_type(4))) float floatx4;
typedef __attribute__((ext_vector_type(4))) int   intx4;

#define MFMA16(a,b,c) __builtin_amdgcn_mfma_f32_16x16x32_bf16((a),(b),(c),0,0,0)

static __device__ __forceinline__ unsigned short f2bf(float f){
    unsigned int u = __float_as_uint(f);
    u = (u + 0x7FFFu + ((u >> 16) & 1u)) >> 16;
    return (unsigned short)u;
}

// pack two f32 -> 2xbf16 in one u32 (low = first arg)
static __device__ __forceinline__ unsigned int pkbf(float lo, float hi){
    unsigned int r;
    asm("v_cvt_pk_bf16_f32 %0, %1, %2" : "=v"(r) : "v"(lo), "v"(hi));
    return r;
}

// async global->LDS, 16 B/lane; lds base must be wave-uniform, lane i lands at
// base + i*16 (m97/m104). Source address is per-lane (gather) -> lets us store
// XOR-swizzled layouts by permuting the SOURCE, not the destination.
static __device__ __forceinline__ void async16(const unsigned short* g, const unsigned short* l){
    __builtin_amdgcn_global_load_lds(
        (const __attribute__((address_space(1))) unsigned int*)g,
        (__attribute__((address_space(3))) unsigned int*)l, 16, 0, 0);
}

// ---------------------------------------------------------------------------
// Kernel 1: prep = transpose x + convert weights to bf16 + precompute the
// rel-pos bias table Bp in PER-LANE FRAGMENT ORDER:
//   entry e = ((((h*8+wave)*2+pp)*16+ct)*64+lane)  ->  uint2 (4 bf16 keys)
// so k_fused's loads are fully coalesced (512 B per wave-instr).
// Values pre-scaled by log2e.
// ---------------------------------------------------------------------------
__global__ __launch_bounds__(256) void k_prep(const float* __restrict__ x,
                                              unsigned short* __restrict__ xT,
                                              const float* __restrict__ qkvw,
                                              unsigned short* __restrict__ wqkv,
                                              const float* __restrict__ outw,
                                              unsigned short* __restrict__ wout,
                                              const float* __restrict__ rel,
                                              unsigned short* __restrict__ Bp){
    __shared__ unsigned short tile[64][78];
    const int bid = blockIdx.x;
    const int tid = threadIdx.x;
    if (bid < 2048){
        const int c0 = (bid & 7) * 64;
        const int n0 = ((bid >> 3) & 3) * 64;
        const int b  = bid >> 5;
        const int chunk = tid & 7;
        const int r     = tid >> 3;
        const float*    src = x  + (size_t)b * 131072;
        unsigned short* dst = xT + (size_t)b * 131072;
#pragma unroll
        for (int it = 0; it < 2; ++it){
            int c = r + it * 32;
            const float* p = src + (size_t)(c0 + c) * 256 + n0 + chunk * 8;
            float4 f0 = *(const float4*)(p);
            float4 f1 = *(const float4*)(p + 4);
            short8 v;
            v[0]=(short)f2bf(f0.x); v[1]=(short)f2bf(f0.y); v[2]=(short)f2bf(f0.z); v[3]=(short)f2bf(f0.w);
            v[4]=(short)f2bf(f1.x); v[5]=(short)f2bf(f1.y); v[6]=(short)f2bf(f1.z); v[7]=(short)f2bf(f1.w);
            *(short8*)&tile[c][chunk * 8] = v;
        }
        __syncthreads();
#pragma unroll
        for (int it = 0; it < 2; ++it){
            int n = r + it * 32;
            short8 o;
#pragma unroll
            for (int e = 0; e < 8; ++e) o[e] = (short)tile[chunk * 8 + e][n];
            *(short8*)(dst + (size_t)(n0 + n) * 512 + c0 + chunk * 8) = o;
        }
    } else if (bid < 3072){
        int i = (bid - 2048) * 256 + tid;
        const float* s; unsigned short* d; int j;
        if (i < 196608){ s = qkvw; d = wqkv; j = i; }
        else { j = i - 196608; if (j >= 65536) return; s = outw; d = wout; }
        float4 f = *(const float4*)(s + (size_t)j * 4);
        uint2 v;
        v.x = (unsigned int)f2bf(f.x) | ((unsigned int)f2bf(f.y) << 16);
        v.y = (unsigned int)f2bf(f.z) | ((unsigned int)f2bf(f.w) << 16);
        *(uint2*)(d + (size_t)j * 4) = v;
    } else {
        // bias table in per-lane fragment order (see header comment)
        int idx  = (bid - 3072) * 256 + tid;           // 0..131071
        int lane = idx & 63;
        int ct   = (idx >> 6) & 15;
        int pp   = (idx >> 10) & 1;
        int wv   = (idx >> 11) & 7;
        int h    = idx >> 14;
        int token = wv * 32 + pp * 16 + (lane & 15);
        int key0  = 32 * (ct >> 1) + 8 * (lane >> 4) + 4 * (ct & 1);
        int th = token >> 4, tw = token & 15;
        int kh = key0 >> 4,  kw0 = key0 & 15;
        int base = h * 961 + (th - kh + 15) * 31 + (tw - kw0 + 15);
        float v0 = rel[base]     * 1.44269504f;
        float v1 = rel[base - 1] * 1.44269504f;
        float v2 = rel[base - 2] * 1.44269504f;
        float v3 = rel[base - 3] * 1.44269504f;
        uint2 o; o.x = pkbf(v0, v1); o.y = pkbf(v2, v3);
        *(uint2*)(Bp + (size_t)idx * 4) = o;
    }
}

// ---------------------------------------------------------------------------
// Kernel 2: FUSED qkv-projection + attention, one block per (b, h).
// Bias loads issued AFTER the phase-A GEMM loop (final vmcnt(0) already
// drained, so T4 counting untouched), BEFORE the epilogue scatter: latency
// hides under the scatter, and the epilogue __syncthreads (vmcnt(0)) drains
// them for free. Register pressure in the hot GEMM loop = round-3 level.
// Phase A: DMA double-buffered mini-GEMM, counted vmcnt + raw barriers.
// Phase B: swapped-operand attention, bias via MFMA C-init, pp-fused K/V.
// ---------------------------------------------------------------------------
__global__ __launch_bounds__(512, 2) void k_fused(const unsigned short* __restrict__ xT,
                                                  const unsigned short* __restrict__ wbf,
                                                  const float* __restrict__ qkvb,
                                                  const unsigned short* __restrict__ Bp,
                                                  unsigned short* __restrict__ ao){
    __shared__ unsigned short SH[77824];          // 155,648 B
    const int XS = 0;          // X stage buf0  256x64
    const int WS = 16384;      // W stage buf0  192x64
    const int QS = 28672;      // Q 256x64   (doubles as X stage buf1 in phase A)
    const int KS = 45056;      // K 256x64   (doubles as W stage buf1 in phase A)
    const int VS = 61440;      // V  64x256 (head-major)

    const int bid  = blockIdx.x;
    const int xcd  = bid & 7;
    const int slot = bid >> 3;                    // 0..63
    const int b = xcd * 8 + (slot & 7);           // all 8 heads of a b-octet on one XCD
    const int h = slot >> 3;
    const int tid  = threadIdx.x;
    const int wave = tid >> 6;
    const int lane = tid & 63;
    const int lrow = lane & 15;
    const int lgrp = lane >> 4;
    const int mq = wave >> 1;                     // M-quarter (64 tokens)
    const int nh = wave & 1;                      // N-half (96 cols)

    // ---- phase A: QKV mini-GEMM -------------------------------------------
    floatx4 acc[4][6];
#pragma unroll
    for (int i = 0; i < 4; ++i)
#pragma unroll
        for (int j = 0; j < 6; ++j){ floatx4 z = {0.f,0.f,0.f,0.f}; acc[i][j] = z; }

    const unsigned short* xb = xT + (size_t)(b * 256) * 512;
    const unsigned short* xsrc[4]; int xdo[4];
#pragma unroll
    for (int c = 0; c < 4; ++c){
        int s   = (c * 8 + wave) * 64 + lane;     // 0..2047
        int row = s >> 3, pch = s & 7;
        int sch = pch ^ (row & 7);
        xsrc[c] = xb + (size_t)row * 512 + sch * 8;
        xdo[c]  = (c * 8 + wave) * 512;
    }
    const unsigned short* wsrc[3]; int wdo[3];
#pragma unroll
    for (int c = 0; c < 3; ++c){
        int s   = (c * 8 + wave) * 64 + lane;     // 0..1535
        int row = s >> 3, pch = s & 7;
        int sch = pch ^ (row & 7);
        int grow = (row >> 6) * 512 + h * 64 + (row & 63);   // q/k/v row slices
        wsrc[c] = wbf + (size_t)grow * 512 + sch * 8;
        wdo[c]  = (c * 8 + wave) * 512;
    }

    auto stageA = [&](int XBs, int WBs, int kk){
#pragma unroll
        for (int c = 0; c < 4; ++c) async16(xsrc[c] + kk, &SH[XBs + xdo[c]]);
#pragma unroll
        for (int c = 0; c < 3; ++c) async16(wsrc[c] + kk, &SH[WBs + wdo[c]]);
    };
    auto compA = [&](int XBs, int WBs){
#pragma unroll
        for (int ks = 0; ks < 2; ++ks){
            short8 af[4], bq[6];
#pragma unroll
            for (int mt = 0; mt < 4; ++mt){
                int row = mq * 64 + mt * 16 + lrow;
                int pch = (ks * 4 + lgrp) ^ (row & 7);
                af[mt] = *(const short8*)&SH[XBs + row * 64 + pch * 8];
            }
#pragma unroll
            for (int nt = 0; nt < 6; ++nt){
                int row = nh * 96 + nt * 16 + lrow;
                int pch = (ks * 4 + lgrp) ^ (row & 7);
                bq[nt] = *(const short8*)&SH[WBs + row * 64 + pch * 8];
            }
#pragma unroll
            for (int mt = 0; mt < 4; ++mt)
#pragma unroll
                for (int nt = 0; nt < 6; ++nt)
                    acc[mt][nt] = MFMA16(af[mt], bq[nt], acc[mt][nt]);
        }
    };

    // T4 pipeline: 2 tiles in flight; counted vmcnt leaves prefetch flying.
    stageA(XS, WS, 0);                            // tile 0 (7 loads)
    stageA(QS, KS, 64);                           // tile 1 (7 loads)
#pragma unroll
    for (int t2 = 0; t2 < 4; ++t2){
        // even tile 2*t2 in buf0
        asm volatile("s_waitcnt vmcnt(7)" ::: "memory");
        __builtin_amdgcn_s_barrier();
        asm volatile("" ::: "memory");
        compA(XS, WS);
        asm volatile("" ::: "memory");
        if (t2 < 3){
            __builtin_amdgcn_s_barrier();         // all waves done reading buf0
            stageA(XS, WS, t2 * 128 + 128);       // tile 2*t2+2 -> buf0
            asm volatile("s_waitcnt vmcnt(7)" ::: "memory");
        } else {
            asm volatile("s_waitcnt vmcnt(0)" ::: "memory");
        }
        // odd tile 2*t2+1 in buf1
        __builtin_amdgcn_s_barrier();
        asm volatile("" ::: "memory");
        compA(QS, KS);
        asm volatile("" ::: "memory");
        __builtin_amdgcn_s_barrier();             // done reading buf1 (or guard epilogue)
        if (t2 < 3) stageA(QS, KS, t2 * 128 + 192);  // tile 2*t2+3 -> buf1
    }

    // ---- bias loads: issued here (all DMAs drained), complete by the
    // epilogue __syncthreads. Live range = epilogue only.
    const uint2* bpw = (const uint2*)Bp + (((size_t)h * 8 + wave) * 2) * 1024 + lane;
    uint2 bA[16], bB[16];
#pragma unroll
    for (int ct = 0; ct < 16; ++ct){
        bA[ct] = bpw[ct * 64];
        bB[ct] = bpw[(16 + ct) * 64];
    }
    asm volatile("" ::: "memory");                // pin loads above the scatter

    // epilogue A: +bias, bf16, scatter into Q/K/V LDS.
    // Q pre-scaled by 0.125*log2e; K rows go to permuted slot rho^-1(token).
#pragma unroll
    for (int mt = 0; mt < 4; ++mt){
#pragma unroll
        for (int nt = 0; nt < 6; ++nt){
            int col = nh * 96 + nt * 16 + lrow;
            int seg = col >> 6, off = col & 63;
            float bv = qkvb[seg * 512 + h * 64 + off];
            int token0 = mq * 64 + mt * 16 + lgrp * 4;
            if (seg == 2){
                int lch = token0 >> 3;
                int pch = (lch & 24) | ((lch & 7) ^ (off & 7));
                uint2 vv;
                vv.x = pkbf(acc[mt][nt][0] + bv, acc[mt][nt][1] + bv);
                vv.y = pkbf(acc[mt][nt][2] + bv, acc[mt][nt][3] + bv);
                *(uint2*)&SH[VS + off * 256 + pch * 8 + (lgrp & 1) * 4] = vv;
            } else if (seg == 1){
#pragma unroll
                for (int r = 0; r < 4; ++r){
                    int token = token0 + r;
                    int kslot = (token & ~0x1C) | ((token & 4) << 2) | ((token & 0x18) >> 1);
                    int pch   = (off >> 3) ^ (kslot & 7);
                    SH[KS + kslot * 64 + pch * 8 + (off & 7)] = f2bf(acc[mt][nt][r] + bv);
                }
            } else {
#pragma unroll
                for (int r = 0; r < 4; ++r){
                    int token = token0 + r;
                    int pch   = (off >> 3) ^ (token & 7);
                    SH[QS + token * 64 + pch * 8 + (off & 7)] =
                        f2bf((acc[mt][nt][r] + bv) * 0.18033688f);
                }
            }
        }
    }
    __syncthreads();

    // ---- phase B: attention (LDS read-only, pp-fused: K/V read ONCE) -------
    short8 aq[2][2];
#pragma unroll
    for (int pp = 0; pp < 2; ++pp)
#pragma unroll
        for (int kc = 0; kc < 2; ++kc){
            int row = wave * 32 + pp * 16 + lrow;
            int pch = (kc * 4 + lgrp) ^ (row & 7);
            aq[pp][kc] = *(const short8*)&SH[QS + row * 64 + pch * 8];
        }

    // S^T = K.Q^T for both pp; C initialized with (register-resident) bias
    floatx4 st0[16], st1[16];
    __builtin_amdgcn_s_setprio(1);
#pragma unroll
    for (int ct = 0; ct < 16; ++ct){
        int row  = ct * 16 + lrow;
        int pch0 = lgrp ^ (row & 7);
        short8 k0 = *(const short8*)&SH[KS + row * 64 + pch0 * 8];
        short8 k1 = *(const short8*)&SH[KS + row * 64 + (pch0 ^ 4) * 8];
        floatx4 z0, z1;
        z0[0] = __uint_as_float(bA[ct].x << 16);
        z0[1] = __uint_as_float(bA[ct].x & 0xFFFF0000u);
        z0[2] = __uint_as_float(bA[ct].y << 16);
        z0[3] = __uint_as_float(bA[ct].y & 0xFFFF0000u);
        z1[0] = __uint_as_float(bB[ct].x << 16);
        z1[1] = __uint_as_float(bB[ct].x & 0xFFFF0000u);
        z1[2] = __uint_as_float(bB[ct].y << 16);
        z1[3] = __uint_as_float(bB[ct].y & 0xFFFF0000u);
        z0 = MFMA16(k0, aq[0][0], z0);
        z0 = MFMA16(k1, aq[0][1], z0);
        z1 = MFMA16(k0, aq[1][0], z1);
        z1 = MFMA16(k1, aq[1][1], z1);
        st0[ct] = z0; st1[ct] = z1;
    }
    __builtin_amdgcn_s_setprio(0);

    // softmax in exp2 domain, 4 independent partial-sum chains per pp
    float inv0, inv1;
    {
        float p0=0.f,p1=0.f,p2=0.f,p3=0.f;
#pragma unroll
        for (int ct = 0; ct < 16; ++ct){
            float e0 = __builtin_amdgcn_exp2f(st0[ct][0]); st0[ct][0]=e0; p0+=e0;
            float e1 = __builtin_amdgcn_exp2f(st0[ct][1]); st0[ct][1]=e1; p1+=e1;
            float e2 = __builtin_amdgcn_exp2f(st0[ct][2]); st0[ct][2]=e2; p2+=e2;
            float e3 = __builtin_amdgcn_exp2f(st0[ct][3]); st0[ct][3]=e3; p3+=e3;
        }
        float s = (p0+p1)+(p2+p3);
        s += __shfl_xor(s, 16, 64);
        s += __shfl_xor(s, 32, 64);
        inv0 = 1.f / s;
    }
    {
        float p0=0.f,p1=0.f,p2=0.f,p3=0.f;
#pragma unroll
        for (int ct = 0; ct < 16; ++ct){
            float e0 = __builtin_amdgcn_exp2f(st1[ct][0]); st1[ct][0]=e0; p0+=e0;
            float e1 = __builtin_amdgcn_exp2f(st1[ct][1]); st1[ct][1]=e1; p1+=e1;
            float e2 = __builtin_amdgcn_exp2f(st1[ct][2]); st1[ct][2]=e2; p2+=e2;
            float e3 = __builtin_amdgcn_exp2f(st1[ct][3]); st1[ct][3]=e3; p3+=e3;
        }
        float s = (p0+p1)+(p2+p3);
        s += __shfl_xor(s, 16, 64);
        s += __shfl_xor(s, 32, 64);
        inv1 = 1.f / s;
    }

    // pack P^T fragments (lane-local thanks to K slot permutation)
    intx4 pf0[8], pf1[8];
#pragma unroll
    for (int ms = 0; ms < 8; ++ms){
        intx4 t0_, t1_;
        t0_.x = (int)pkbf(st0[2*ms  ][0], st0[2*ms  ][1]);
        t0_.y = (int)pkbf(st0[2*ms  ][2], st0[2*ms  ][3]);
        t0_.z = (int)pkbf(st0[2*ms+1][0], st0[2*ms+1][1]);
        t0_.w = (int)pkbf(st0[2*ms+1][2], st0[2*ms+1][3]);
        pf0[ms] = t0_;
        t1_.x = (int)pkbf(st1[2*ms  ][0], st1[2*ms  ][1]);
        t1_.y = (int)pkbf(st1[2*ms  ][2], st1[2*ms  ][3]);
        t1_.z = (int)pkbf(st1[2*ms+1][0], st1[2*ms+1][1]);
        t1_.w = (int)pkbf(st1[2*ms+1][2], st1[2*ms+1][3]);
        pf1[ms] = t1_;
    }

    // O^T = V^T . P^T, both pp per V-fragment read
    unsigned short* aob = ao + (size_t)(b * 256) * 512 + h * 64;
    const int n0 = wave * 32 + lrow;
    __builtin_amdgcn_s_setprio(1);
#pragma unroll
    for (int dt = 0; dt < 4; ++dt){
        floatx4 a0 = {0.f,0.f,0.f,0.f}, a1 = {0.f,0.f,0.f,0.f};
#pragma unroll
        for (int ms = 0; ms < 8; ++ms){
            int row = dt * 16 + lrow;
            int lch = ms * 4 + lgrp;
            int pch = (lch & 24) | ((lch & 7) ^ (row & 7));
            short8 vb = *(const short8*)&SH[VS + row * 256 + pch * 8];
            a0 = MFMA16(vb, __builtin_bit_cast(short8, pf0[ms]), a0);
            a1 = MFMA16(vb, __builtin_bit_cast(short8, pf1[ms]), a1);
        }
        uint2 o0, o1;
        o0.x = pkbf(a0[0] * inv0, a0[1] * inv0);
        o0.y = pkbf(a0[2] * inv0, a0[3] * inv0);
        *(uint2*)(aob + (size_t)n0 * 512 + dt * 16 + lgrp * 4) = o0;
        o1.x = pkbf(a1[0] * inv1, a1[1] * inv1);
        o1.y = pkbf(a1[2] * inv1, a1[3] * inv1);
        *(uint2*)(aob + (size_t)(n0 + 16) * 512 + dt * 16 + lgrp * 4) = o1;
    }
    __builtin_amdgcn_s_setprio(0);
}

// ---------------------------------------------------------------------------
// Kernel 3: out projection, double-buffered with COUNTED vmcnt (T4), XCD
// swizzle, chunk-XOR LDS swizzle, fp32 out[b,o,n].
// ---------------------------------------------------------------------------
__global__ __launch_bounds__(256, 2) void k_out(const unsigned short* __restrict__ ao,
                                                const unsigned short* __restrict__ wbf,
                                                const float* __restrict__ bias,
                                                float* __restrict__ out){
    __shared__ unsigned short Ash[2][2][128][32];   // [dbuf][kslice][row][col]
    __shared__ unsigned short Bsh[2][2][128][32];
    const int bid  = blockIdx.x;
    const int xcd  = bid & 7;
    const int slot = bid >> 3;
    const int t0 = (xcd * 16 + (slot & 15)) * 128;
    const int o0 = (slot >> 4) * 128;
    const int tid  = threadIdx.x;
    const int wave = tid >> 6;
    const int lane = tid & 63;
    const int lrow = lane & 15;
    const int wm   = (wave >> 1) * 64;
    const int wn   = (wave & 1) * 64;
    const int ld_row = wave * 32 + (lane >> 2);
    const int ld_col = (((lane & 3) ^ ((lane >> 3) & 3))) * 8;
    const int pcho = (((lane >> 4) ^ ((lrow >> 1) & 3))) * 8;

    floatx4 acc[4][4];
#pragma unroll
    for (int i = 0; i < 4; ++i)
#pragma unroll
        for (int j = 0; j < 4; ++j){ floatx4 z = {0.f,0.f,0.f,0.f}; acc[i][j] = z; }

    const unsigned short* gA = wbf + (size_t)(o0 + ld_row) * 512 + ld_col;
    const unsigned short* gB = ao  + (size_t)(t0 + ld_row) * 512 + ld_col;

    auto stage = [&](int d, int kk){
        async16(gA + kk,                 &Ash[d][0][wave * 32][0]);
        async16(gA + kk + 16 * 512,      &Ash[d][0][wave * 32 + 16][0]);
        async16(gA + kk + 32,            &Ash[d][1][wave * 32][0]);
        async16(gA + kk + 32 + 16 * 512, &Ash[d][1][wave * 32 + 16][0]);
        async16(gB + kk,                 &Bsh[d][0][wave * 32][0]);
        async16(gB + kk + 16 * 512,      &Bsh[d][0][wave * 32 + 16][0]);
        async16(gB + kk + 32,            &Bsh[d][1][wave * 32][0]);
        async16(gB + kk + 32 + 16 * 512, &Bsh[d][1][wave * 32 + 16][0]);
    };
    auto comp = [&](int d){
#pragma unroll
        for (int s = 0; s < 2; ++s){
            short8 af[4], bq[4];
#pragma unroll
            for (int mt = 0; mt < 4; ++mt) af[mt] = *(const short8*)&Ash[d][s][wm + mt*16 + lrow][pcho];
#pragma unroll
            for (int nt = 0; nt < 4; ++nt) bq[nt] = *(const short8*)&Bsh[d][s][wn + nt*16 + lrow][pcho];
#pragma unroll
            for (int mt = 0; mt < 4; ++mt)
#pragma unroll
                for (int nt = 0; nt < 4; ++nt)
                    acc[mt][nt] = MFMA16(af[mt], bq[nt], acc[mt][nt]);
        }
    };

    stage(0, 0);
    stage(1, 64);
#pragma unroll
    for (int t2 = 0; t2 < 4; ++t2){
        asm volatile("s_waitcnt vmcnt(8)" ::: "memory");
        __builtin_amdgcn_s_barrier();
        asm volatile("" ::: "memory");
        comp(0);
        asm volatile("" ::: "memory");
        if (t2 < 3){
            __builtin_amdgcn_s_barrier();
            stage(0, t2 * 128 + 128);
            asm volatile("s_waitcnt vmcnt(8)" ::: "memory");
        } else {
            asm volatile("s_waitcnt vmcnt(0)" ::: "memory");
        }
        __builtin_amdgcn_s_barrier();
        asm volatile("" ::: "memory");
        comp(1);
        asm volatile("" ::: "memory");
        __builtin_amdgcn_s_barrier();
        if (t2 < 3) stage(1, t2 * 128 + 192);
    }
#pragma unroll
    for (int mt = 0; mt < 4; ++mt){
        int orow0 = o0 + wm + mt*16 + (lane >> 4) * 4;
#pragma unroll
        for (int nt = 0; nt < 4; ++nt){
            int tcol = t0 + wn + nt*16 + lrow;
            int bb = tcol >> 8, nn = tcol & 255;
#pragma unroll
            for (int r = 0; r < 4; ++r){
                float bv = bias[orow0 + r];
                out[(size_t)(bb * 512 + orow0 + r) * 256 + nn] = acc[mt][nt][r] + bv;
            }
        }
    }
}

// ---------------------------------------------------------------------------
extern "C" void kernel_launch(void* const* d_in, const int* in_sizes, int n_in,
                              void* d_out, int out_size, void* d_ws, size_t ws_size,
                              hipStream_t stream){
    const float* x    = (const float*)d_in[0];
    const float* qkvw = (const float*)d_in[1];
    const float* qkvb = (const float*)d_in[2];
    const float* outw = (const float*)d_in[3];
    const float* outb = (const float*)d_in[4];
    const float* rel  = (const float*)d_in[5];
    float* out = (float*)d_out;

    // workspace: XT (16 MiB) | AO (16 MiB) | wqkv 1.5M | wout 0.5M | Bp 1M
    const size_t XT_OFF = 0;
    const size_t AO_OFF = 16777216;
    const size_t W_OFF  = 33554432;
    const size_t NEED   = W_OFF + 4194304;
    if (ws_size < NEED) return;

    char* ws = (char*)d_ws;
    unsigned short* xT = (unsigned short*)(ws + XT_OFF);
    unsigned short* ao = (unsigned short*)(ws + AO_OFF);
    unsigned short* wqkv_bf = (unsigned short*)(ws + W_OFF);
    unsigned short* wout_bf = (unsigned short*)(ws + W_OFF + 2097152);
    unsigned short* Bp      = (unsigned short*)(ws + W_OFF + 2621440);

    hipLaunchKernelGGL(k_prep,  dim3(3584), dim3(256), 0, stream,
                       x, xT, qkvw, wqkv_bf, outw, wout_bf, rel, Bp);
    hipLaunchKernelGGL(k_fused, dim3(512),  dim3(512), 0, stream,
                       xT, wqkv_bf, qkvb, Bp, ao);
    hipLaunchKernelGGL(k_out,   dim3(512),  dim3(256), 0, stream,
                       ao, wout_bf, outb, out);
}